// Round 1
// baseline (231.336 us; speedup 1.0000x reference)
//
#include <hip/hip_runtime.h>

// Problem constants (B=32, C=3, H=480, W=640)
#define HW    307200     // H*W
#define HW4   76800      // HW/4
#define CHW   921600     // 3*HW
#define RED_BPB 60       // reduce blocks per batch: 60*256*4*5 == HW exactly

// ---------------------------------------------------------------------------
// Pass 1: per-(output)batch mean of gray(clip(x*bf, 0, 1))
// One f64 atomicAdd per block into d_ws[b].
// ---------------------------------------------------------------------------
__global__ __launch_bounds__(256) void cr_reduce_gray(
    const float* __restrict__ x,
    const float* __restrict__ bright,
    double* __restrict__ mean_ws,
    int ns)
{
    int b   = blockIdx.x / RED_BPB;     // output-batch index
    int blk = blockIdx.x % RED_BPB;
    int b_in = (ns == 1) ? b : (b / ns);

    const float4* rp = (const float4*)(x + (size_t)b_in * CHW);
    const float4* gp = rp + HW4;
    const float4* bp = gp + HW4;
    float bf = bright[b];

    float acc = 0.0f;
    for (int p = blk * 256 + threadIdx.x; p < HW4; p += RED_BPB * 256) {
        float4 r = rp[p];
        float4 g = gp[p];
        float4 bl = bp[p];
        #pragma unroll
        for (int k = 0; k < 4; ++k) {
            float rr = fminf(fmaxf(((const float*)&r)[k]  * bf, 0.0f), 1.0f);
            float gg = fminf(fmaxf(((const float*)&g)[k]  * bf, 0.0f), 1.0f);
            float bb = fminf(fmaxf(((const float*)&bl)[k] * bf, 0.0f), 1.0f);
            acc += 0.299f * rr + 0.587f * gg + 0.114f * bb;
        }
    }

    // wave(64) shuffle reduce
    #pragma unroll
    for (int off = 32; off > 0; off >>= 1)
        acc += __shfl_down(acc, off);

    __shared__ float wsum[4];
    int lane = threadIdx.x & 63;
    int wave = threadIdx.x >> 6;
    if (lane == 0) wsum[wave] = acc;
    __syncthreads();
    if (threadIdx.x == 0) {
        float s = wsum[0] + wsum[1] + wsum[2] + wsum[3];
        atomicAdd(&mean_ws[b], (double)s);
    }
}

// ---------------------------------------------------------------------------
// Pass 2: elementwise brightness -> contrast blend -> saturation blend -> hue
// ---------------------------------------------------------------------------
__device__ __forceinline__ void cr_process(
    float r, float g, float b,
    float bf, float cf, float sf, float hf, float mean,
    float& ro, float& go, float& bo)
{
    // brightness
    r = fminf(fmaxf(r * bf, 0.0f), 1.0f);
    g = fminf(fmaxf(g * bf, 0.0f), 1.0f);
    b = fminf(fmaxf(b * bf, 0.0f), 1.0f);
    // contrast: blend with per-batch mean
    float omc = 1.0f - cf;
    r = fminf(fmaxf(cf * r + omc * mean, 0.0f), 1.0f);
    g = fminf(fmaxf(cf * g + omc * mean, 0.0f), 1.0f);
    b = fminf(fmaxf(cf * b + omc * mean, 0.0f), 1.0f);
    // saturation: blend with per-pixel gray
    float gray = 0.299f * r + 0.587f * g + 0.114f * b;
    float oms = 1.0f - sf;
    r = fminf(fmaxf(sf * r + oms * gray, 0.0f), 1.0f);
    g = fminf(fmaxf(sf * g + oms * gray, 0.0f), 1.0f);
    b = fminf(fmaxf(sf * b + oms * gray, 0.0f), 1.0f);

    // hue adjust (RGB -> h,s,v -> shift h -> RGB)
    float maxc = fmaxf(r, fmaxf(g, b));
    float minc = fminf(r, fminf(g, b));
    float v  = maxc;
    float cr = maxc - minc;
    float crd = (cr == 0.0f) ? 1.0f : cr;
    float invcrd = 1.0f / crd;
    float md = (maxc == 0.0f) ? 1.0f : maxc;
    float s = cr / md;
    float rc = (maxc - r) * invcrd;
    float gc = (maxc - g) * invcrd;
    float bc = (maxc - b) * invcrd;

    float h = (maxc == r) ? (bc - gc)
            : ((maxc == g) ? (2.0f + rc - bc)
                           : (4.0f + gc - rc));
    h = h * (1.0f / 6.0f);
    h = h - floorf(h);      // python-style mod 1
    h = h + hf;
    h = h - floorf(h);

    float i6 = h * 6.0f;
    float fi = floorf(i6);
    float f  = i6 - fi;
    int i = ((int)fi) % 6;   // fi in [0,6]; 6 aliases to 0 with f==0 (continuous)

    float p = v * (1.0f - s);
    float q = v * (1.0f - f * s);
    float t = v * (1.0f - (1.0f - f) * s);

    ro = (i == 0 || i == 5) ? v : (i == 1 ? q : (i == 4 ? t : p));
    go = (i == 1 || i == 2) ? v : (i == 0 ? t : (i == 3 ? q : p));
    bo = (i == 3 || i == 4) ? v : (i == 5 ? q : (i == 2 ? t : p));
}

__global__ __launch_bounds__(256) void cr_apply(
    const float* __restrict__ x,
    const float* __restrict__ bright,
    const float* __restrict__ contrast,
    const float* __restrict__ sat,
    const float* __restrict__ hue,
    const double* __restrict__ mean_ws,
    float* __restrict__ out,
    int ns, int n)                 // n = B_out * HW4
{
    int idx = blockIdx.x * blockDim.x + threadIdx.x;
    if (idx >= n) return;
    int b  = idx / HW4;            // constant divisor -> magic mul
    int p4 = idx - b * HW4;
    int b_in = (ns == 1) ? b : (b / ns);

    const float4* rp = (const float4*)(x + (size_t)b_in * CHW);
    const float4* gp = rp + HW4;
    const float4* bp = gp + HW4;
    float4* orp = (float4*)(out + (size_t)b * CHW);
    float4* ogp = orp + HW4;
    float4* obp = ogp + HW4;

    float bf = bright[b];
    float cf = contrast[b];
    float sf = sat[b];
    float hf = hue[b];
    float mean = (float)(mean_ws[b] * (1.0 / (double)HW));

    float4 r = rp[p4];
    float4 g = gp[p4];
    float4 bl = bp[p4];
    float4 ro, go, bo;

    cr_process(r.x, g.x, bl.x, bf, cf, sf, hf, mean, ro.x, go.x, bo.x);
    cr_process(r.y, g.y, bl.y, bf, cf, sf, hf, mean, ro.y, go.y, bo.y);
    cr_process(r.z, g.z, bl.z, bf, cf, sf, hf, mean, ro.z, go.z, bo.z);
    cr_process(r.w, g.w, bl.w, bf, cf, sf, hf, mean, ro.w, go.w, bo.w);

    orp[p4] = ro;
    ogp[p4] = go;
    obp[p4] = bo;
}

extern "C" void kernel_launch(void* const* d_in, const int* in_sizes, int n_in,
                              void* d_out, int out_size, void* d_ws, size_t ws_size,
                              hipStream_t stream) {
    const float* x  = (const float*)d_in[0];
    const float* bf = (const float*)d_in[1];
    const float* cf = (const float*)d_in[2];
    const float* sf = (const float*)d_in[3];
    const float* hf = (const float*)d_in[4];
    float* out = (float*)d_out;

    int ns = out_size / in_sizes[0];
    if (ns < 1) ns = 1;
    int B_out = out_size / CHW;

    double* mean_ws = (double*)d_ws;
    hipMemsetAsync(mean_ws, 0, (size_t)B_out * sizeof(double), stream);

    cr_reduce_gray<<<dim3(B_out * RED_BPB), dim3(256), 0, stream>>>(
        x, bf, mean_ws, ns);

    int n = B_out * HW4;
    cr_apply<<<dim3((n + 255) / 256), dim3(256), 0, stream>>>(
        x, bf, cf, sf, hf, mean_ws, out, ns, n);
}

// Round 4
// 227.017 us; speedup vs baseline: 1.0190x; 1.0190x over previous
//
#include <hip/hip_runtime.h>

// Problem constants (B=32, C=3, H=480, W=640)
#define HW      307200     // H*W
#define HW4     76800      // HW/4 (float4 groups per plane)
#define CHW     921600     // 3*HW
#define RED_BPB 60         // reduce blocks per batch: 60*256*5*4 == HW exactly
#define APP_BPB 300        // apply blocks per batch: 300*256   == HW4 exactly

// native clang vector type — required by __builtin_nontemporal_store
typedef float vfloat4 __attribute__((ext_vector_type(4)));

struct RGB { float r, g, b; };

// ---------------------------------------------------------------------------
// Pass 1: per-(output)batch partial sums of gray(clip(x*bf, 0, 1))
// Block (b, blk) writes its partial to ws[b*RED_BPB + blk]. No atomics,
// no memset needed (every slot is written every call).
// ---------------------------------------------------------------------------
__global__ __launch_bounds__(256) void cr_reduce_gray(
    const float* __restrict__ x,
    const float* __restrict__ bright,
    float* __restrict__ part_ws,
    int ns)
{
    int b   = blockIdx.x / RED_BPB;     // output-batch index (uniform)
    int blk = blockIdx.x % RED_BPB;
    int b_in = (ns == 1) ? b : (b / ns);

    const vfloat4* rp = (const vfloat4*)(x + (size_t)b_in * CHW);
    const vfloat4* gp = rp + HW4;
    const vfloat4* bp = gp + HW4;
    float bf = bright[b];

    float acc = 0.0f;
    #pragma unroll
    for (int it = 0; it < 5; ++it) {
        int p = blk * 256 + threadIdx.x + it * (RED_BPB * 256);
        vfloat4 r  = rp[p];
        vfloat4 g  = gp[p];
        vfloat4 bl = bp[p];
        #pragma unroll
        for (int k = 0; k < 4; ++k) {
            float rr = fminf(fmaxf(r[k]  * bf, 0.0f), 1.0f);
            float gg = fminf(fmaxf(g[k]  * bf, 0.0f), 1.0f);
            float bb = fminf(fmaxf(bl[k] * bf, 0.0f), 1.0f);
            acc += 0.299f * rr + 0.587f * gg + 0.114f * bb;
        }
    }

    // wave(64) shuffle reduce
    #pragma unroll
    for (int off = 32; off > 0; off >>= 1)
        acc += __shfl_down(acc, off);

    __shared__ float wsum[4];
    int lane = threadIdx.x & 63;
    int wave = threadIdx.x >> 6;
    if (lane == 0) wsum[wave] = acc;
    __syncthreads();
    if (threadIdx.x == 0)
        part_ws[b * RED_BPB + blk] = wsum[0] + wsum[1] + wsum[2] + wsum[3];
}

// ---------------------------------------------------------------------------
// Pass 2: elementwise brightness -> contrast blend -> saturation blend -> hue
// ---------------------------------------------------------------------------
__device__ __forceinline__ RGB cr_process(
    float r, float g, float b,
    float bf, float cf, float sf, float hf, float cmean)
{
    // brightness
    r = fminf(fmaxf(r * bf, 0.0f), 1.0f);
    g = fminf(fmaxf(g * bf, 0.0f), 1.0f);
    b = fminf(fmaxf(b * bf, 0.0f), 1.0f);
    // contrast: cmean = (1-cf)*mean precomputed (uniform)
    r = fminf(fmaxf(cf * r + cmean, 0.0f), 1.0f);
    g = fminf(fmaxf(cf * g + cmean, 0.0f), 1.0f);
    b = fminf(fmaxf(cf * b + cmean, 0.0f), 1.0f);
    // saturation: blend with per-pixel gray
    float gray = 0.299f * r + 0.587f * g + 0.114f * b;
    float oms = (1.0f - sf) * gray;
    r = fminf(fmaxf(sf * r + oms, 0.0f), 1.0f);
    g = fminf(fmaxf(sf * g + oms, 0.0f), 1.0f);
    b = fminf(fmaxf(sf * b + oms, 0.0f), 1.0f);

    // hue adjust (RGB -> h,s,v -> shift h -> RGB)
    float maxc = fmaxf(r, fmaxf(g, b));
    float minc = fminf(r, fminf(g, b));
    float v  = maxc;
    float cr = maxc - minc;
    float crd = (cr == 0.0f) ? 1.0f : cr;
    float invcrd = 1.0f / crd;
    float md = (maxc == 0.0f) ? 1.0f : maxc;
    float s = cr / md;
    float rc = (maxc - r) * invcrd;
    float gc = (maxc - g) * invcrd;
    float bc = (maxc - b) * invcrd;

    float h = (maxc == r) ? (bc - gc)
            : ((maxc == g) ? (2.0f + rc - bc)
                           : (4.0f + gc - rc));
    h = h * (1.0f / 6.0f);
    h = h - floorf(h);      // python-style mod 1
    h = h + hf;
    h = h - floorf(h);

    float i6 = h * 6.0f;
    float fi = floorf(i6);
    float f  = i6 - fi;
    int i = ((int)fi) % 6;   // fi in [0,6]; 6 aliases to 0 with f==0 (continuous)

    float p = v * (1.0f - s);
    float q = v * (1.0f - f * s);
    float t = v * (1.0f - (1.0f - f) * s);

    RGB o;
    o.r = (i == 0 || i == 5) ? v : (i == 1 ? q : (i == 4 ? t : p));
    o.g = (i == 1 || i == 2) ? v : (i == 0 ? t : (i == 3 ? q : p));
    o.b = (i == 3 || i == 4) ? v : (i == 5 ? q : (i == 2 ? t : p));
    return o;
}

__global__ __launch_bounds__(256) void cr_apply(
    const float* __restrict__ x,
    const float* __restrict__ bright,
    const float* __restrict__ contrast,
    const float* __restrict__ sat,
    const float* __restrict__ hue,
    const float* __restrict__ part_ws,
    float* __restrict__ out,
    int ns)
{
    int b    = blockIdx.x / APP_BPB;          // uniform per block
    int pblk = blockIdx.x % APP_BPB;
    int p4   = pblk * 256 + threadIdx.x;
    int b_in = (ns == 1) ? b : (b / ns);

    // broadcast mean: one wave sums the 60 partials
    __shared__ float smean;
    if (threadIdx.x < 64) {
        float v = (threadIdx.x < RED_BPB) ? part_ws[b * RED_BPB + threadIdx.x] : 0.0f;
        #pragma unroll
        for (int off = 32; off > 0; off >>= 1)
            v += __shfl_down(v, off);
        if (threadIdx.x == 0) smean = v * (1.0f / (float)HW);
    }
    __syncthreads();

    const vfloat4* rp = (const vfloat4*)(x + (size_t)b_in * CHW);
    const vfloat4* gp = rp + HW4;
    const vfloat4* bp = gp + HW4;
    vfloat4* orp = (vfloat4*)(out + (size_t)b * CHW);
    vfloat4* ogp = orp + HW4;
    vfloat4* obp = ogp + HW4;

    float bf = bright[b];
    float cf = contrast[b];
    float sf = sat[b];
    float hf = hue[b];
    float cmean = (1.0f - cf) * smean;

    vfloat4 r  = rp[p4];
    vfloat4 g  = gp[p4];
    vfloat4 bl = bp[p4];
    vfloat4 ro, go, bo;

    #pragma unroll
    for (int k = 0; k < 4; ++k) {
        RGB o = cr_process(r[k], g[k], bl[k], bf, cf, sf, hf, cmean);
        ro[k] = o.r;
        go[k] = o.g;
        bo[k] = o.b;
    }

    // non-temporal stores: out is never re-read; keep x resident in L2/L3
    __builtin_nontemporal_store(ro, &orp[p4]);
    __builtin_nontemporal_store(go, &ogp[p4]);
    __builtin_nontemporal_store(bo, &obp[p4]);
}

extern "C" void kernel_launch(void* const* d_in, const int* in_sizes, int n_in,
                              void* d_out, int out_size, void* d_ws, size_t ws_size,
                              hipStream_t stream) {
    const float* x  = (const float*)d_in[0];
    const float* bf = (const float*)d_in[1];
    const float* cf = (const float*)d_in[2];
    const float* sf = (const float*)d_in[3];
    const float* hf = (const float*)d_in[4];
    float* out = (float*)d_out;

    int ns = out_size / in_sizes[0];
    if (ns < 1) ns = 1;
    int B_out = out_size / CHW;

    float* part_ws = (float*)d_ws;   // B_out * RED_BPB floats, fully rewritten each call

    cr_reduce_gray<<<dim3(B_out * RED_BPB), dim3(256), 0, stream>>>(
        x, bf, part_ws, ns);

    cr_apply<<<dim3(B_out * APP_BPB), dim3(256), 0, stream>>>(
        x, bf, cf, sf, hf, part_ws, out, ns);
}